// Round 4
// baseline (387.842 us; speedup 1.0000x reference)
//
#include <hip/hip_runtime.h>

// DIAGNOSTIC ROUND: real kernel launched 4x (idempotent) to measure the
// marginal per-launch cost via dur_us delta, since the harness's reset
// machinery (~245 us of fills/restores) hides our dispatch from top-5.
// out[b,l,d] = log( sum_e gates[b,e] * exp(xs[e,b,l,d]) ), eps if sum==0
// E=8, B=128, L=96, D=512. ~226 MB traffic/call -> ~36 us HBM floor.

typedef float f32x4 __attribute__((ext_vector_type(4)));

constexpr int E_   = 8;
constexpr int B_   = 128;
constexpr int LD_  = 96 * 512;        // 49152 scalars per (b) row
constexpr int N_   = B_ * LD_;        // 6291456 scalars per expert
constexpr int NV4  = N_ / 4;          // 1572864 float4s per expert
// Each block: 256 threads x 2 float4 = 512 float4s. LD_/4=12288 float4s per b
// -> 24 blocks per b -> b is block-uniform. Grid = NV4/512 = 3072 blocks.

__global__ __launch_bounds__(256) void moe_log_combine_kernel(
    const float* __restrict__ xs,      // [E, B, L, D]
    const float* __restrict__ gates,   // [B, E]
    float* __restrict__ out)           // [B, L, D]
{
    const f32x4* __restrict__ xs4  = reinterpret_cast<const f32x4*>(xs);
    f32x4* __restrict__       out4 = reinterpret_cast<f32x4*>(out);

    const int blk = blockIdx.x;               // 0..3071
    const int b   = blk / 24;                 // block-uniform batch index (SALU)

    // gates[b, 0..7] — block-uniform -> scalar loads
    float g[E_];
#pragma unroll
    for (int e = 0; e < E_; ++e) g[e] = gates[b * E_ + e];

    const int i0 = blk * 512 + (int)threadIdx.x;  // float4 index, 32-bit
    const int i1 = i0 + 256;

    f32x4 a0 = {0.f, 0.f, 0.f, 0.f};
    f32x4 a1 = {0.f, 0.f, 0.f, 0.f};

#pragma unroll
    for (int e = 0; e < E_; ++e) {
        const f32x4 x0 = xs4[e * NV4 + i0];
        const f32x4 x1 = xs4[e * NV4 + i1];
        const float ge = g[e];
#pragma unroll
        for (int j = 0; j < 4; ++j) {
            a0[j] = fmaf(ge, __expf(x0[j]), a0[j]);
            a1[j] = fmaf(ge, __expf(x1[j]), a1[j]);
        }
    }

    // reference: combined[combined==0] = float32(np.finfo(np.float64).eps)
    const float eps = 2.220446049250313e-16f;
    f32x4 r0, r1;
#pragma unroll
    for (int j = 0; j < 4; ++j) {
        const float c0 = (a0[j] == 0.f) ? eps : a0[j];
        const float c1 = (a1[j] == 0.f) ? eps : a1[j];
        r0[j] = __logf(c0);
        r1[j] = __logf(c1);
    }

    __builtin_nontemporal_store(r0, out4 + i0);
    __builtin_nontemporal_store(r1, out4 + i1);
}

extern "C" void kernel_launch(void* const* d_in, const int* in_sizes, int n_in,
                              void* d_out, int out_size, void* d_ws, size_t ws_size,
                              hipStream_t stream) {
    const float* xs    = (const float*)d_in[0];   // [E,B,L,D] fp32
    const float* gates = (const float*)d_in[1];   // [B,E] fp32
    float* out = (float*)d_out;                   // [B,L,D] fp32

    const int grid = NV4 / 512;   // 3072 blocks, 256 threads, 2 float4/thread

    // 4 identical launches (idempotent). Launches 2-4 are L3-warm; the dur_us
    // delta vs the single-launch round measures the marginal kernel cost.
    for (int rep = 0; rep < 4; ++rep) {
        moe_log_combine_kernel<<<grid, 256, 0, stream>>>(xs, gates, out);
    }
}

// Round 5
// 279.243 us; speedup vs baseline: 1.3889x; 1.3889x over previous
//
#include <hip/hip_runtime.h>

// out[b,l,d] = log( sum_e gates[b,e] * exp(xs[e,b,l,d]) ), eps if sum==0
// E=8, B=128, L=96, D=512. ~226.5 MB traffic/call.
//
// ROOFLINE EVIDENCE (round-4 diagnostic): 4x-launch probe measured marginal
// cost = (387.84-280.89)/3 = 35.65 us/launch = 6.35 TB/s -- at the achievable
// HBM ceiling (6.3 TB/s ubench; fills in the same harness hit 6.7-6.8).
// Reported dur_us ~281 = ~245 us harness reset (805 MB ws 0xAA fill = 119 us
// + ~250 small restore dispatches) + ~36 us kernel. Kernel is at the memory
// floor: every xs element read exactly once, E-reduction fused, output
// written once; transcendentals hide under the stream.

typedef float f32x4 __attribute__((ext_vector_type(4)));

constexpr int E_   = 8;
constexpr int B_   = 128;
constexpr int LD_  = 96 * 512;        // 49152 scalars per (b) row
constexpr int N_   = B_ * LD_;        // 6291456 scalars per expert
constexpr int NV4  = N_ / 4;          // 1572864 float4s per expert
// Each block: 256 threads x 2 float4 = 512 float4s. LD_/4=12288 float4s per b
// -> 24 blocks per b -> b is block-uniform. Grid = NV4/512 = 3072 blocks.

__global__ __launch_bounds__(256) void moe_log_combine_kernel(
    const float* __restrict__ xs,      // [E, B, L, D]
    const float* __restrict__ gates,   // [B, E]
    float* __restrict__ out)           // [B, L, D]
{
    const f32x4* __restrict__ xs4  = reinterpret_cast<const f32x4*>(xs);
    f32x4* __restrict__       out4 = reinterpret_cast<f32x4*>(out);

    const int blk = blockIdx.x;               // 0..3071
    const int b   = blk / 24;                 // block-uniform batch index (SALU)

    // gates[b, 0..7] — block-uniform -> scalar loads
    float g[E_];
#pragma unroll
    for (int e = 0; e < E_; ++e) g[e] = gates[b * E_ + e];

    const int i0 = blk * 512 + (int)threadIdx.x;  // float4 index, 32-bit
    const int i1 = i0 + 256;

    f32x4 a0 = {0.f, 0.f, 0.f, 0.f};
    f32x4 a1 = {0.f, 0.f, 0.f, 0.f};

#pragma unroll
    for (int e = 0; e < E_; ++e) {
        const f32x4 x0 = xs4[e * NV4 + i0];
        const f32x4 x1 = xs4[e * NV4 + i1];
        const float ge = g[e];
#pragma unroll
        for (int j = 0; j < 4; ++j) {
            a0[j] = fmaf(ge, __expf(x0[j]), a0[j]);
            a1[j] = fmaf(ge, __expf(x1[j]), a1[j]);
        }
    }

    // reference: combined[combined==0] = float32(np.finfo(np.float64).eps)
    const float eps = 2.220446049250313e-16f;
    f32x4 r0, r1;
#pragma unroll
    for (int j = 0; j < 4; ++j) {
        const float c0 = (a0[j] == 0.f) ? eps : a0[j];
        const float c1 = (a1[j] == 0.f) ? eps : a1[j];
        r0[j] = __logf(c0);
        r1[j] = __logf(c1);
    }

    // non-temporal stores: keep the 25 MB output out of the cache hierarchy
    __builtin_nontemporal_store(r0, out4 + i0);
    __builtin_nontemporal_store(r1, out4 + i1);
}

extern "C" void kernel_launch(void* const* d_in, const int* in_sizes, int n_in,
                              void* d_out, int out_size, void* d_ws, size_t ws_size,
                              hipStream_t stream) {
    const float* xs    = (const float*)d_in[0];   // [E,B,L,D] fp32
    const float* gates = (const float*)d_in[1];   // [B,E] fp32
    float* out = (float*)d_out;                   // [B,L,D] fp32

    const int grid = NV4 / 512;   // 3072 blocks, 256 threads, 2 float4/thread
    moe_log_combine_kernel<<<grid, 256, 0, stream>>>(xs, gates, out);
}